// Round 12
// baseline (140.840 us; speedup 1.0000x reference)
//
#include <hip/hip_runtime.h>
#include <hip/hip_bf16.h>
#include <stdint.h>

#define DD 256
#define NB 16
#define NN 1024
#define MTOT (NB * NN)  // 16384

typedef __attribute__((ext_vector_type(8))) short short8;
typedef __attribute__((ext_vector_type(4))) float f32x4;

__device__ __forceinline__ ushort f2b(float f) {
  uint32_t u = __float_as_uint(f);
  return (ushort)((u + 0x7fffu + ((u >> 16) & 1u)) >> 16);
}

// ---------------------------------------------------------------------------
// C[m][e] = sum_k A[m][k] * W[e][k] + bias[e];  M=16384, K=E=256
template <bool A_F32, bool WRITE_T>
__global__ __launch_bounds__(256, 1) void gemm_hqk(
    const void* __restrict__ Aptr, const float* __restrict__ W,
    const float* __restrict__ bias, ushort* __restrict__ C,
    ushort* __restrict__ CT) {
  __shared__ ushort Wl[256 * 256];  // 128 KB, bf16, XOR-swizzled
  const int tid = threadIdx.x;

  for (int i = 0; i < 64; ++i) {
    int idx4 = i * 256 + tid;
    int row = idx4 >> 6;
    int col0 = (idx4 & 63) << 2;
    float4 v = ((const float4*)W)[idx4];
    ushort4 b4;
    b4.x = f2b(v.x); b4.y = f2b(v.y); b4.z = f2b(v.z); b4.w = f2b(v.w);
    int byte = (row * 512 + col0 * 2) ^ ((row & 7) << 4);
    *(ushort4*)((char*)Wl + byte) = b4;
  }
  __syncthreads();

  const int w = tid >> 6, lane = tid & 63, l15 = lane & 15, hi = lane >> 4;
  const int m0 = blockIdx.x * 64 + w * 16;
  const int arow = m0 + l15;

  f32x4 acc[16] = {};

#pragma unroll
  for (int kk = 0; kk < 8; ++kk) {
    const int k0 = kk * 32 + hi * 8;
    short8 a;
    if constexpr (A_F32) {
      const float4* ap = (const float4*)((const float*)Aptr + arow * 256 + k0);
      float4 x = ap[0], y = ap[1];
      a[0] = (short)f2b(x.x); a[1] = (short)f2b(x.y);
      a[2] = (short)f2b(x.z); a[3] = (short)f2b(x.w);
      a[4] = (short)f2b(y.x); a[5] = (short)f2b(y.y);
      a[6] = (short)f2b(y.z); a[7] = (short)f2b(y.w);
    } else {
      a = *(const short8*)((const ushort*)Aptr + arow * 256 + k0);
    }
#pragma unroll
    for (int et = 0; et < 16; ++et) {
      int er = et * 16 + l15;
      short8 bf = *(const short8*)((const char*)Wl +
                                   ((er * 512 + k0 * 2) ^ ((er & 7) << 4)));
      acc[et] = __builtin_amdgcn_mfma_f32_16x16x32_bf16(a, bf, acc[et], 0, 0, 0);
    }
  }

  ushort hvals[16][4];
#pragma unroll
  for (int et = 0; et < 16; ++et) {
    int e = et * 16 + l15;
    float bv = bias[e];
#pragma unroll
    for (int r = 0; r < 4; ++r) {
      ushort hb = f2b(acc[et][r] + bv);
      hvals[et][r] = hb;
      C[(m0 + hi * 4 + r) * 256 + e] = hb;
    }
  }

  if constexpr (WRITE_T) {
    __syncthreads();  // done reading Wl; reuse as transpose buffer [256][64]
    ushort* Tl = Wl;
    const int mloc = w * 16 + hi * 4;
#pragma unroll
    for (int et = 0; et < 16; ++et)
#pragma unroll
      for (int r = 0; r < 4; ++r)
        Tl[(et * 16 + l15) * 64 + mloc + r] = hvals[et][r];
    __syncthreads();
    const int bidx = blockIdx.x >> 4;
    const int n0 = (blockIdx.x & 15) * 64;
    ushort* dst = CT + bidx * (256 * 1024) + tid * 1024 + n0;
    const uint4* src = (const uint4*)(Tl + tid * 64);
#pragma unroll
    for (int j = 0; j < 8; ++j) ((uint4*)dst)[j] = src[j];
  }
}

// ---------------------------------------------------------------------------
// Fused q+k GEMM: 512 blocks; [0,256) -> q from Q weights, [256,512) -> k.
__global__ __launch_bounds__(256, 1) void gemm_qk(
    const ushort* __restrict__ h, const float* __restrict__ Qw,
    const float* __restrict__ Qb, const float* __restrict__ Kw,
    const float* __restrict__ Kb_, ushort* __restrict__ q,
    ushort* __restrict__ k) {
  __shared__ ushort Wl[256 * 256];
  const int tid = threadIdx.x;
  const bool isK = blockIdx.x >= 256;
  const float* W = isK ? Kw : Qw;
  const float* bias = isK ? Kb_ : Qb;
  ushort* C = isK ? k : q;
  const int bid = blockIdx.x & 255;

  for (int i = 0; i < 64; ++i) {
    int idx4 = i * 256 + tid;
    int row = idx4 >> 6;
    int col0 = (idx4 & 63) << 2;
    float4 v = ((const float4*)W)[idx4];
    ushort4 b4;
    b4.x = f2b(v.x); b4.y = f2b(v.y); b4.z = f2b(v.z); b4.w = f2b(v.w);
    int byte = (row * 512 + col0 * 2) ^ ((row & 7) << 4);
    *(ushort4*)((char*)Wl + byte) = b4;
  }
  __syncthreads();

  const int w = tid >> 6, lane = tid & 63, l15 = lane & 15, hi = lane >> 4;
  const int m0 = bid * 64 + w * 16;
  const int arow = m0 + l15;

  f32x4 acc[16] = {};

#pragma unroll
  for (int kk = 0; kk < 8; ++kk) {
    const int k0 = kk * 32 + hi * 8;
    short8 a = *(const short8*)(h + arow * 256 + k0);
#pragma unroll
    for (int et = 0; et < 16; ++et) {
      int er = et * 16 + l15;
      short8 bf = *(const short8*)((const char*)Wl +
                                   ((er * 512 + k0 * 2) ^ ((er & 7) << 4)));
      acc[et] = __builtin_amdgcn_mfma_f32_16x16x32_bf16(a, bf, acc[et], 0, 0, 0);
    }
  }

#pragma unroll
  for (int et = 0; et < 16; ++et) {
    int e = et * 16 + l15;
    float bv = bias[e];
#pragma unroll
    for (int r = 0; r < 4; ++r)
      C[(m0 + hi * 4 + r) * 256 + e] = f2b(acc[et][r] + bv);
  }
}

// ---------------------------------------------------------------------------
// Fused attention, r10 structure with KVBLK=128 (8 tiles instead of 16):
// same total staging volume, half the per-tile fixed cost (barriers + exposed
// latency). 8 waves, wave-pair key split (half*64 keys), fixed-max softmax,
// in-loop graph->bitmask pack (double-buffered M2).
#define SM_KT 0         // ushort Kt[128*256]  65536 B
#define SM_HT 65536     // ushort Ht[256*128]  65536 B
#define SM_PL 131072    // ushort Pl[8*16*64]  16384 B
#define SM_M2 147456    // uint   M2[2][64][4]  2048 B
#define SM_CM 149504    // float  Cm[64]         256 B
#define SM_SZ 149760

// P-buffer swizzle (128-B rows): XOR in bits>=4 keeps 16B blocks intact.
__device__ __forceinline__ int pswz(int row, int bytecol) {
  return (row * 128 + bytecol) ^ ((row & 7) << 4) ^ ((row >> 3) << 5);
}

__global__ __launch_bounds__(512, 2) void attn8(
    const ushort* __restrict__ Q, const ushort* __restrict__ Kb,
    const ushort* __restrict__ HT, const int* __restrict__ graph,
    float* __restrict__ out) {
  __shared__ __align__(16) char smem[SM_SZ];
  ushort* Kt = (ushort*)(smem + SM_KT);
  ushort* Ht = (ushort*)(smem + SM_HT);
  ushort* Pl = (ushort*)(smem + SM_PL);
  uint* M2 = (uint*)(smem + SM_M2);
  float* Cm = (float*)(smem + SM_CM);

  const int tid = threadIdx.x;
  const int w = tid >> 6, lane = tid & 63, l15 = lane & 15, hi = lane >> 4;
  const int wg = w >> 1, half = w & 1;
  // XCD-aware remap: XCD x handles batches {2x, 2x+1}
  const int hw = blockIdx.x;
  const int slot = hw >> 3;
  const int b = (hw & 7) * 2 + (slot >> 4);
  const int q0 = (slot & 15) * 64;
  const int qrow_a = q0 + wg * 16 + l15;
  const int qrow_cl = wg * 16 + hi * 4;  // local row base (+r)
  const int* grow_base = graph + (b * 1024 + q0 + w * 8) * 1024 + lane;

  int greg[16];

  // ---- prologue: graph(0) + Q frags; ballot into M2[0] ----
#pragma unroll
  for (int j = 0; j < 8; ++j) {
    greg[2 * j] = grow_base[j * 1024];
    greg[2 * j + 1] = grow_base[j * 1024 + 64];
  }

  short8 qf[8];
#pragma unroll
  for (int kk = 0; kk < 8; ++kk)
    qf[kk] = *(const short8*)(Q + (b * 1024 + qrow_a) * 256 + kk * 32 + hi * 8);

#pragma unroll
  for (int j = 0; j < 8; ++j) {
    unsigned long long m0 = __ballot(greg[2 * j] != 0);
    unsigned long long m1 = __ballot(greg[2 * j + 1] != 0);
    if (lane == 0) {
      M2[(w * 8 + j) * 4 + 0] = (uint)m0;
      M2[(w * 8 + j) * 4 + 1] = (uint)(m0 >> 32);
      M2[(w * 8 + j) * 4 + 2] = (uint)m1;
      M2[(w * 8 + j) * 4 + 3] = (uint)(m1 >> 32);
    }
  }

  float lR[4] = {0.f, 0.f, 0.f, 0.f};  // per-LANE partial row sums
  f32x4 o[16] = {};

  for (int t = 0; t < 8; ++t) {
    const uint* M2c = M2 + (t & 1) * 256;
    uint* M2n = M2 + ((t & 1) ^ 1) * 256;

    __syncthreads();
#pragma unroll
    for (int i = 0; i < 8; ++i) {  // stage K tile [128][256]
      int c = i * 512 + tid;
      int krow = c >> 5, col0 = (c & 31) << 3;
      uint4 v = *(const uint4*)(Kb + (b * 1024 + t * 128 + krow) * 256 + col0);
      *(uint4*)((char*)Kt + ((krow * 512 + col0 * 2) ^ ((krow & 7) << 4))) = v;
    }
#pragma unroll
    for (int i = 0; i < 8; ++i) {  // stage H^T tile [256][128]
      int c = i * 512 + tid;
      int drow = c >> 4, col0 = (c & 15) << 3;
      uint4 v = *(const uint4*)(HT + b * (256 * 1024) + drow * 1024 + t * 128 + col0);
      *(uint4*)((char*)Ht + ((drow * 256 + col0 * 2) ^ ((drow & 7) << 4))) = v;
    }
    __syncthreads();

    // issue next tile's graph loads NOW; compute covers the HBM latency
    if (t < 7) {
#pragma unroll
      for (int j = 0; j < 8; ++j) {
        greg[2 * j] = grow_base[j * 1024 + (t + 1) * 128];
        greg[2 * j + 1] = grow_base[j * 1024 + (t + 1) * 128 + 64];
      }
    }

    // S = q @ k^T : 16 rows x 64 keys (this wave's half)
    f32x4 s[4] = {};
    __builtin_amdgcn_s_setprio(1);
#pragma unroll
    for (int kk = 0; kk < 8; ++kk) {
#pragma unroll
      for (int nt = 0; nt < 4; ++nt) {
        int krow = half * 64 + nt * 16 + l15;
        short8 kf = *(const short8*)((const char*)Kt +
            ((krow * 512 + (kk * 32 + hi * 8) * 2) ^ ((krow & 7) << 4)));
        s[nt] = __builtin_amdgcn_mfma_f32_16x16x32_bf16(qf[kk], kf, s[nt], 0, 0, 0);
      }
    }
    __builtin_amdgcn_s_setprio(0);

    // scale, leaky, mask, exp — per-lane VALU only
    float p[4][4];
#pragma unroll
    for (int r = 0; r < 4; ++r) {
      uint mw0 = M2c[(qrow_cl + r) * 4 + half * 2];
      uint mw1 = M2c[(qrow_cl + r) * 4 + half * 2 + 1];
#pragma unroll
      for (int nt = 0; nt < 4; ++nt) {
        uint mw = (nt < 2) ? mw0 : mw1;
        uint bit = (mw >> ((nt & 1) * 16 + l15)) & 1u;
        float v = s[nt][r] * 0.0625f;
        v = (v >= 0.f) ? v : 0.2f * v;
        float pv = bit ? __expf(v) : 0.f;
        p[nt][r] = pv;
        lR[r] += pv;
      }
    }

    // P (C-layout) -> per-wave LDS -> A-frag layout
    ushort* Pw = Pl + w * 1024;
#pragma unroll
    for (int nt = 0; nt < 4; ++nt)
#pragma unroll
      for (int r = 0; r < 4; ++r) {
        int row = hi * 4 + r, col = nt * 16 + l15;
        *(ushort*)((char*)Pw + pswz(row, col * 2)) = f2b(p[nt][r]);
      }
    __asm__ volatile("s_waitcnt lgkmcnt(0)" ::: "memory");
    short8 pa[2];
#pragma unroll
    for (int ks = 0; ks < 2; ++ks)
      pa[ks] = *(const short8*)((const char*)Pw + pswz(l15, ks * 64 + hi * 16));

    // O += P @ H (keys half*64 .. half*64+63)
    __builtin_amdgcn_s_setprio(1);
#pragma unroll
    for (int dt = 0; dt < 16; ++dt) {
      int dcol = dt * 16 + l15;
#pragma unroll
      for (int ks = 0; ks < 2; ++ks) {
        short8 hf = *(const short8*)((const char*)Ht +
            ((dcol * 256 + half * 128 + ks * 64 + hi * 16) ^ ((dcol & 7) << 4)));
        o[dt] = __builtin_amdgcn_mfma_f32_16x16x32_bf16(pa[ks], hf, o[dt], 0, 0, 0);
      }
    }
    __builtin_amdgcn_s_setprio(0);

    // pack next tile's mask into the other M2 buffer (readers only run after
    // the loop-top barrier)
    if (t < 7) {
#pragma unroll
      for (int j = 0; j < 8; ++j) {
        unsigned long long m0 = __ballot(greg[2 * j] != 0);
        unsigned long long m1 = __ballot(greg[2 * j + 1] != 0);
        if (lane == 0) {
          M2n[(w * 8 + j) * 4 + 0] = (uint)m0;
          M2n[(w * 8 + j) * 4 + 1] = (uint)(m0 >> 32);
          M2n[(w * 8 + j) * 4 + 2] = (uint)m1;
          M2n[(w * 8 + j) * 4 + 3] = (uint)(m1 >> 32);
        }
      }
    }
  }

  // ---- reduce row sums once (16-lane groups share a row set) ----
#pragma unroll
  for (int r = 0; r < 4; ++r) {
    lR[r] += __shfl_xor(lR[r], 1);
    lR[r] += __shfl_xor(lR[r], 2);
    lR[r] += __shfl_xor(lR[r], 4);
    lR[r] += __shfl_xor(lR[r], 8);
  }

  // ---- combine wave pairs, epilogue ----
  __syncthreads();  // all tiles done; reuse smem[0,64K) (= Kt) as Ob
  float* Ob = (float*)smem;  // 4 pairs x [16][256] fp32 = 64 KB
  if (half == 1) {
#pragma unroll
    for (int dt = 0; dt < 16; ++dt)
#pragma unroll
      for (int r = 0; r < 4; ++r) {
        int row = hi * 4 + r;
        int byte = (row * 1024 + (dt * 16 + l15) * 4) ^ ((row & 15) << 6);
        *(float*)((char*)Ob + wg * 16384 + byte) = o[dt][r];
      }
    if (l15 == 0) {
#pragma unroll
      for (int r = 0; r < 4; ++r)
        Cm[wg * 16 + hi * 4 + r] = lR[r];
    }
  }
  __syncthreads();
  if (half == 0) {
#pragma unroll
    for (int r = 0; r < 4; ++r) {
      int rowl = hi * 4 + r;
      float inv = 1.f / (lR[r] + Cm[wg * 16 + rowl]);
      int orow = b * 1024 + q0 + wg * 16 + rowl;
#pragma unroll
      for (int dt = 0; dt < 16; ++dt) {
        int byte = (rowl * 1024 + (dt * 16 + l15) * 4) ^ ((rowl & 15) << 6);
        float ob = *(const float*)((const char*)Ob + wg * 16384 + byte);
        float v = (o[dt][r] + ob) * inv;
        out[orow * 256 + dt * 16 + l15] = fmaxf(v, 0.f);
      }
    }
  }
}

// ---------------------------------------------------------------------------
extern "C" void kernel_launch(void* const* d_in, const int* in_sizes, int n_in,
                              void* d_out, int out_size, void* d_ws,
                              size_t ws_size, hipStream_t stream) {
  const float* feature = (const float*)d_in[0];
  const int* graph = (const int*)d_in[1];
  const float* W_w = (const float*)d_in[2];
  const float* W_b = (const float*)d_in[3];
  const float* Q_w = (const float*)d_in[4];
  const float* Q_b = (const float*)d_in[5];
  const float* K_w = (const float*)d_in[6];
  const float* K_b = (const float*)d_in[7];
  float* out = (float*)d_out;

  ushort* h = (ushort*)d_ws;          // [B,N,D] bf16   8 MB
  ushort* hT = h + MTOT * DD;         // [B,D,N] bf16   8 MB
  ushort* q = hT + MTOT * DD;         // [B,N,D] bf16   8 MB
  ushort* k = q + MTOT * DD;          // [B,N,D] bf16   8 MB

  gemm_hqk<true, true><<<256, 256, 0, stream>>>(feature, W_w, W_b, h, hT);
  gemm_qk<<<512, 256, 0, stream>>>(h, Q_w, Q_b, K_w, K_b, q, k);
  attn8<<<256, 512, 0, stream>>>(q, k, hT, graph, out);
}

// Round 13
// 93.828 us; speedup vs baseline: 1.5010x; 1.5010x over previous
//
#include <hip/hip_runtime.h>
#include <hip/hip_bf16.h>
#include <stdint.h>

#define DD 256
#define NB 16
#define NN 1024
#define MTOT (NB * NN)  // 16384

typedef __attribute__((ext_vector_type(8))) short short8;
typedef __attribute__((ext_vector_type(4))) float f32x4;

__device__ __forceinline__ ushort f2b(float f) {
  uint32_t u = __float_as_uint(f);
  return (ushort)((u + 0x7fffu + ((u >> 16) & 1u)) >> 16);
}

// Stage a 256x256 fp32 weight matrix into LDS as bf16, XOR-swizzled rows.
__device__ __forceinline__ void stage_weights(const float* __restrict__ W,
                                              ushort* Wl, int tid) {
  for (int i = 0; i < 64; ++i) {
    int idx4 = i * 256 + tid;
    int row = idx4 >> 6;
    int col0 = (idx4 & 63) << 2;
    float4 v = ((const float4*)W)[idx4];
    ushort4 b4;
    b4.x = f2b(v.x); b4.y = f2b(v.y); b4.z = f2b(v.z); b4.w = f2b(v.w);
    int byte = (row * 512 + col0 * 2) ^ ((row & 7) << 4);
    *(ushort4*)((char*)Wl + byte) = b4;
  }
}

// ---------------------------------------------------------------------------
// Fused h/q/k GEMM. Each block owns 64 rows. h never touches HBM row-major:
// compute h in registers -> LDS transpose (Tl) -> (a) write hT global,
// (b) re-read each wave's h A-frags into registers -> stage Q_w -> q ->
// stage K_w -> k. Weight staging volume identical to the split version
// (3*256 = 256+512 block-stagings); saves 8MB h write + 16MB h reads + 1
// launch.
__global__ __launch_bounds__(256, 1) void gemm_fused(
    const float* __restrict__ feature, const float* __restrict__ W_w,
    const float* __restrict__ W_b, const float* __restrict__ Q_w,
    const float* __restrict__ Q_b, const float* __restrict__ K_w,
    const float* __restrict__ K_b, ushort* __restrict__ hT,
    ushort* __restrict__ q, ushort* __restrict__ k) {
  __shared__ ushort Wl[256 * 256];  // 128 KB; doubles as Tl transpose buffer
  const int tid = threadIdx.x;
  const int w = tid >> 6, lane = tid & 63, l15 = lane & 15, hi = lane >> 4;
  const int m0 = blockIdx.x * 64 + w * 16;
  const int arow = m0 + l15;

  // ---- h = feature @ W_w^T + W_b ----
  stage_weights(W_w, Wl, tid);
  __syncthreads();

  f32x4 acc[16] = {};
#pragma unroll
  for (int kk = 0; kk < 8; ++kk) {
    const int k0 = kk * 32 + hi * 8;
    const float4* ap = (const float4*)(feature + arow * 256 + k0);
    float4 x = ap[0], y = ap[1];
    short8 a;
    a[0] = (short)f2b(x.x); a[1] = (short)f2b(x.y);
    a[2] = (short)f2b(x.z); a[3] = (short)f2b(x.w);
    a[4] = (short)f2b(y.x); a[5] = (short)f2b(y.y);
    a[6] = (short)f2b(y.z); a[7] = (short)f2b(y.w);
#pragma unroll
    for (int et = 0; et < 16; ++et) {
      int er = et * 16 + l15;
      short8 bf = *(const short8*)((const char*)Wl +
                                   ((er * 512 + k0 * 2) ^ ((er & 7) << 4)));
      acc[et] = __builtin_amdgcn_mfma_f32_16x16x32_bf16(a, bf, acc[et], 0, 0, 0);
    }
  }

  ushort hvals[16][4];
#pragma unroll
  for (int et = 0; et < 16; ++et) {
    float bv = W_b[et * 16 + l15];
#pragma unroll
    for (int r = 0; r < 4; ++r) hvals[et][r] = f2b(acc[et][r] + bv);
  }

  // ---- transpose h into Tl(=Wl) [256][64] ----
  __syncthreads();  // all waves done reading Wl
  ushort* Tl = Wl;
  {
    const int mloc = w * 16 + hi * 4;
#pragma unroll
    for (int et = 0; et < 16; ++et)
#pragma unroll
      for (int r = 0; r < 4; ++r)
        Tl[(et * 16 + l15) * 64 + mloc + r] = hvals[et][r];
  }
  __syncthreads();

  // ---- (a) h A-frags back to registers; (b) hT to global ----
  short8 qa[8];
#pragma unroll
  for (int kk = 0; kk < 8; ++kk) {
    const int k0 = kk * 32 + hi * 8;
#pragma unroll
    for (int j = 0; j < 8; ++j)
      qa[kk][j] = (short)Tl[(k0 + j) * 64 + w * 16 + l15];
  }
  {
    const int bidx = blockIdx.x >> 4;
    const int n0 = (blockIdx.x & 15) * 64;
    ushort* dst = hT + bidx * (256 * 1024) + tid * 1024 + n0;
    const uint4* src = (const uint4*)(Tl + tid * 64);
#pragma unroll
    for (int j = 0; j < 8; ++j) ((uint4*)dst)[j] = src[j];
  }
  __syncthreads();  // Tl reads done before Q_w staging overwrites

  // ---- q = h @ Q_w^T + Q_b ----
  stage_weights(Q_w, Wl, tid);
  __syncthreads();
#pragma unroll
  for (int et = 0; et < 16; ++et) acc[et] = (f32x4){0.f, 0.f, 0.f, 0.f};
#pragma unroll
  for (int kk = 0; kk < 8; ++kk) {
    const int k0 = kk * 32 + hi * 8;
#pragma unroll
    for (int et = 0; et < 16; ++et) {
      int er = et * 16 + l15;
      short8 bf = *(const short8*)((const char*)Wl +
                                   ((er * 512 + k0 * 2) ^ ((er & 7) << 4)));
      acc[et] = __builtin_amdgcn_mfma_f32_16x16x32_bf16(qa[kk], bf, acc[et], 0, 0, 0);
    }
  }
#pragma unroll
  for (int et = 0; et < 16; ++et) {
    int e = et * 16 + l15;
    float bv = Q_b[e];
#pragma unroll
    for (int r = 0; r < 4; ++r)
      q[(m0 + hi * 4 + r) * 256 + e] = f2b(acc[et][r] + bv);
  }
  __syncthreads();  // q-compute reads of Wl done before K_w staging

  // ---- k = h @ K_w^T + K_b ----
  stage_weights(K_w, Wl, tid);
  __syncthreads();
#pragma unroll
  for (int et = 0; et < 16; ++et) acc[et] = (f32x4){0.f, 0.f, 0.f, 0.f};
#pragma unroll
  for (int kk = 0; kk < 8; ++kk) {
    const int k0 = kk * 32 + hi * 8;
#pragma unroll
    for (int et = 0; et < 16; ++et) {
      int er = et * 16 + l15;
      short8 bf = *(const short8*)((const char*)Wl +
                                   ((er * 512 + k0 * 2) ^ ((er & 7) << 4)));
      acc[et] = __builtin_amdgcn_mfma_f32_16x16x32_bf16(qa[kk], bf, acc[et], 0, 0, 0);
    }
  }
#pragma unroll
  for (int et = 0; et < 16; ++et) {
    int e = et * 16 + l15;
    float bv = K_b[e];
#pragma unroll
    for (int r = 0; r < 4; ++r)
      k[(m0 + hi * 4 + r) * 256 + e] = f2b(acc[et][r] + bv);
  }
}

// ---------------------------------------------------------------------------
// Fused attention (round-10 winner, byte-identical): 8 waves, wave-pair key
// split, fixed-max softmax, in-loop graph->bitmask pack (double-buffered M2).
#define SM_KT 0        // ushort Kt[64*256]   32768 B
#define SM_HT 32768    // ushort Ht[256*64]   32768 B
#define SM_PL 65536    // ushort Pl[8*16*32]   8192 B
#define SM_M2 73728    // uint   M2[2][128]    1024 B
#define SM_CM 74752    // float  Cm[64]         256 B
#define SM_SZ 75008

// P-buffer swizzle: XOR in bits>=4 keeps 16B blocks intact for ds_read_b128.
__device__ __forceinline__ int pswz(int row, int bytecol) {
  return (row * 64 + bytecol) ^ ((row & 7) << 4) ^ ((row >> 3) << 5);
}

__global__ __launch_bounds__(512, 2) void attn8(
    const ushort* __restrict__ Q, const ushort* __restrict__ Kb,
    const ushort* __restrict__ HT, const int* __restrict__ graph,
    float* __restrict__ out) {
  __shared__ __align__(16) char smem[SM_SZ];
  ushort* Kt = (ushort*)(smem + SM_KT);
  ushort* Ht = (ushort*)(smem + SM_HT);
  ushort* Pl = (ushort*)(smem + SM_PL);
  uint* M2 = (uint*)(smem + SM_M2);
  float* Cm = (float*)(smem + SM_CM);

  const int tid = threadIdx.x;
  const int w = tid >> 6, lane = tid & 63, l15 = lane & 15, hi = lane >> 4;
  const int wg = w >> 1, half = w & 1;
  // XCD-aware remap: XCD x handles batches {2x, 2x+1}
  const int hw = blockIdx.x;
  const int slot = hw >> 3;
  const int b = (hw & 7) * 2 + (slot >> 4);
  const int q0 = (slot & 15) * 64;
  const int qrow_a = q0 + wg * 16 + l15;
  const int qrow_cl = wg * 16 + hi * 4;  // local row base (+r)
  const int* grow_base = graph + (b * 1024 + q0 + w * 8) * 1024 + lane;

  int greg[8];

  // ---- prologue: graph(0) + Q frags; ballot into M2[0] ----
#pragma unroll
  for (int j = 0; j < 8; ++j) greg[j] = grow_base[j * 1024];

  short8 qf[8];
#pragma unroll
  for (int kk = 0; kk < 8; ++kk)
    qf[kk] = *(const short8*)(Q + (b * 1024 + qrow_a) * 256 + kk * 32 + hi * 8);

#pragma unroll
  for (int j = 0; j < 8; ++j) {
    unsigned long long mm = __ballot(greg[j] != 0);
    if (lane == 0) {
      M2[(w * 8 + j) * 2] = (uint)mm;
      M2[(w * 8 + j) * 2 + 1] = (uint)(mm >> 32);
    }
  }

  float lR[4] = {0.f, 0.f, 0.f, 0.f};  // per-LANE partial row sums
  f32x4 o[16] = {};

  for (int t = 0; t < 16; ++t) {
    const uint* M2c = M2 + (t & 1) * 128;
    uint* M2n = M2 + ((t & 1) ^ 1) * 128;

    __syncthreads();
#pragma unroll
    for (int i = 0; i < 4; ++i) {  // stage K tile [64][256]
      int c = i * 512 + tid;
      int krow = c >> 5, col0 = (c & 31) << 3;
      uint4 v = *(const uint4*)(Kb + (b * 1024 + t * 64 + krow) * 256 + col0);
      *(uint4*)((char*)Kt + ((krow * 512 + col0 * 2) ^ ((krow & 7) << 4))) = v;
    }
#pragma unroll
    for (int i = 0; i < 4; ++i) {  // stage H^T tile [256][64]
      int c = i * 512 + tid;
      int drow = c >> 3, col0 = (c & 7) << 3;
      uint4 v = *(const uint4*)(HT + b * (256 * 1024) + drow * 1024 + t * 64 + col0);
      *(uint4*)((char*)Ht + ((drow * 128 + col0 * 2) ^ ((drow & 7) << 4))) = v;
    }
    __syncthreads();

    // issue next tile's graph loads NOW; compute covers the HBM latency
    if (t < 15) {
#pragma unroll
      for (int j = 0; j < 8; ++j) greg[j] = grow_base[j * 1024 + (t + 1) * 64];
    }

    // S = q @ k^T : 16 rows x 32 keys (this wave's half)
    f32x4 s[2] = {};
    __builtin_amdgcn_s_setprio(1);
#pragma unroll
    for (int kk = 0; kk < 8; ++kk) {
#pragma unroll
      for (int nt = 0; nt < 2; ++nt) {
        int krow = half * 32 + nt * 16 + l15;
        short8 kf = *(const short8*)((const char*)Kt +
            ((krow * 512 + (kk * 32 + hi * 8) * 2) ^ ((krow & 7) << 4)));
        s[nt] = __builtin_amdgcn_mfma_f32_16x16x32_bf16(qf[kk], kf, s[nt], 0, 0, 0);
      }
    }
    __builtin_amdgcn_s_setprio(0);

    // scale, leaky, mask, exp — per-lane VALU only
    float p[2][4];
#pragma unroll
    for (int r = 0; r < 4; ++r) {
      uint mw = M2c[(qrow_cl + r) * 2 + half];
      float v0 = s[0][r] * 0.0625f; v0 = (v0 >= 0.f) ? v0 : 0.2f * v0;
      float v1 = s[1][r] * 0.0625f; v1 = (v1 >= 0.f) ? v1 : 0.2f * v1;
      float p0 = ((mw >> l15) & 1u) ? __expf(v0) : 0.f;
      float p1 = ((mw >> (16 + l15)) & 1u) ? __expf(v1) : 0.f;
      p[0][r] = p0; p[1][r] = p1;
      lR[r] += p0 + p1;
    }

    // P (C-layout) -> per-wave LDS -> A-frag layout
    ushort* Pw = Pl + w * 512;
#pragma unroll
    for (int nt = 0; nt < 2; ++nt)
#pragma unroll
      for (int r = 0; r < 4; ++r) {
        int row = hi * 4 + r, col = nt * 16 + l15;
        *(ushort*)((char*)Pw + pswz(row, col * 2)) = f2b(p[nt][r]);
      }
    __asm__ volatile("s_waitcnt lgkmcnt(0)" ::: "memory");
    short8 pa = *(const short8*)((const char*)Pw + pswz(l15, hi * 16));

    // O += P @ H (keys half*32 .. half*32+31)
    __builtin_amdgcn_s_setprio(1);
#pragma unroll
    for (int dt = 0; dt < 16; ++dt) {
      int dcol = dt * 16 + l15;
      short8 hf = *(const short8*)((const char*)Ht +
          ((dcol * 128 + (half * 32 + hi * 8) * 2) ^ ((dcol & 7) << 4)));
      o[dt] = __builtin_amdgcn_mfma_f32_16x16x32_bf16(pa, hf, o[dt], 0, 0, 0);
    }
    __builtin_amdgcn_s_setprio(0);

    // pack next tile's mask into the other M2 buffer (race-free: readers of
    // M2n only run after the loop-top barrier)
    if (t < 15) {
#pragma unroll
      for (int j = 0; j < 8; ++j) {
        unsigned long long mm = __ballot(greg[j] != 0);
        if (lane == 0) {
          M2n[(w * 8 + j) * 2] = (uint)mm;
          M2n[(w * 8 + j) * 2 + 1] = (uint)(mm >> 32);
        }
      }
    }
  }

  // ---- reduce row sums once (16-lane groups share a row set) ----
#pragma unroll
  for (int r = 0; r < 4; ++r) {
    lR[r] += __shfl_xor(lR[r], 1);
    lR[r] += __shfl_xor(lR[r], 2);
    lR[r] += __shfl_xor(lR[r], 4);
    lR[r] += __shfl_xor(lR[r], 8);
  }

  // ---- combine wave pairs, epilogue ----
  __syncthreads();  // all tiles done; reuse smem[0,64K) = Kt+Ht as Ob
  float* Ob = (float*)smem;  // 4 pairs x [16][256] fp32 = 64 KB
  if (half == 1) {
#pragma unroll
    for (int dt = 0; dt < 16; ++dt)
#pragma unroll
      for (int r = 0; r < 4; ++r) {
        int row = hi * 4 + r;
        int byte = (row * 1024 + (dt * 16 + l15) * 4) ^ ((row & 15) << 6);
        *(float*)((char*)Ob + wg * 16384 + byte) = o[dt][r];
      }
    if (l15 == 0) {
#pragma unroll
      for (int r = 0; r < 4; ++r)
        Cm[wg * 16 + hi * 4 + r] = lR[r];
    }
  }
  __syncthreads();
  if (half == 0) {
#pragma unroll
    for (int r = 0; r < 4; ++r) {
      int rowl = hi * 4 + r;
      float inv = 1.f / (lR[r] + Cm[wg * 16 + rowl]);
      int orow = b * 1024 + q0 + wg * 16 + rowl;
#pragma unroll
      for (int dt = 0; dt < 16; ++dt) {
        int byte = (rowl * 1024 + (dt * 16 + l15) * 4) ^ ((rowl & 15) << 6);
        float ob = *(const float*)((const char*)Ob + wg * 16384 + byte);
        float v = (o[dt][r] + ob) * inv;
        out[orow * 256 + dt * 16 + l15] = fmaxf(v, 0.f);
      }
    }
  }
}

// ---------------------------------------------------------------------------
extern "C" void kernel_launch(void* const* d_in, const int* in_sizes, int n_in,
                              void* d_out, int out_size, void* d_ws,
                              size_t ws_size, hipStream_t stream) {
  const float* feature = (const float*)d_in[0];
  const int* graph = (const int*)d_in[1];
  const float* W_w = (const float*)d_in[2];
  const float* W_b = (const float*)d_in[3];
  const float* Q_w = (const float*)d_in[4];
  const float* Q_b = (const float*)d_in[5];
  const float* K_w = (const float*)d_in[6];
  const float* K_b = (const float*)d_in[7];
  float* out = (float*)d_out;

  ushort* hT = (ushort*)d_ws;         // [B,D,N] bf16   8 MB
  ushort* q = hT + MTOT * DD;         // [B,N,D] bf16   8 MB
  ushort* k = q + MTOT * DD;          // [B,N,D] bf16   8 MB

  gemm_fused<<<256, 256, 0, stream>>>(feature, W_w, W_b, Q_w, Q_b, K_w, K_b,
                                      hT, q, k);
  attn8<<<256, 512, 0, stream>>>(q, k, hT, graph, out);
}